// Round 7
// baseline (1176.883 us; speedup 1.0000x reference)
//
#include <hip/hip_runtime.h>

#define NH 4     // heads
#define CH 64    // channels/head

// ---------------- encoder: h = relu(x @ W + b); x:[N,8], W:[8,64] ----------------
__global__ void encoder_kernel(const float* __restrict__ x, const float* __restrict__ W,
                               const float* __restrict__ b, float* __restrict__ h, int N) {
  int idx = blockIdx.x * blockDim.x + threadIdx.x;
  if (idx >= N * 64) return;
  int n = idx >> 6, j = idx & 63;
  const float* xp = x + n * 8;
  float acc = b[j];
#pragma unroll
  for (int k = 0; k < 8; ++k) acc = fmaf(xp[k], W[k * 64 + j], acc);
  h[idx] = fmaxf(acc, 0.0f);
}

// ------- xl = h@Wl + bl, xr = h@Wr + br (both fp32); h:[N,K], W:[K,256] -------
template <int K>
__global__ void lin_lr_kernel(const float* __restrict__ h,
                              const float* __restrict__ Wl, const float* __restrict__ bl,
                              const float* __restrict__ Wr, const float* __restrict__ br,
                              float* __restrict__ xl, float* __restrict__ xr, int N) {
  __shared__ float hs[8][K];
  int n0 = blockIdx.x * 8;
  int j = threadIdx.x;  // output column
  int nmax = N - n0; if (nmax > 8) nmax = 8;
  for (int idx = j; idx < nmax * K; idx += 256) {
    int m = idx / K, k = idx % K;
    hs[m][k] = h[(size_t)(n0 + m) * K + k];
  }
  __syncthreads();
  float accl[8], accr[8];
  float bjl = bl[j], bjr = br[j];
#pragma unroll
  for (int m = 0; m < 8; ++m) { accl[m] = bjl; accr[m] = bjr; }
  for (int k = 0; k < K; ++k) {
    float wl = Wl[k * 256 + j];
    float wr = Wr[k * 256 + j];
#pragma unroll
    for (int m = 0; m < 8; ++m) {
      accl[m] = fmaf(hs[m][k], wl, accl[m]);
      accr[m] = fmaf(hs[m][k], wr, accr[m]);
    }
  }
  for (int m = 0; m < nmax; ++m) {
    xl[(size_t)(n0 + m) * 256 + j] = accl[m];
    xr[(size_t)(n0 + m) * 256 + j] = accr[m];
  }
}

// ---------------- CSR build (counting sort by dst), fully parallel scan ----------------
__global__ void hist_kernel(const int* __restrict__ dst, int* __restrict__ deg, int E) {
  int e = blockIdx.x * blockDim.x + threadIdx.x;
  if (e < E) atomicAdd(&deg[dst[e]], 1);
}

__global__ void scan_partial_kernel(const int* __restrict__ deg, int* __restrict__ partial, int N) {
  __shared__ int sm[256];
  int t = threadIdx.x;
  int i = blockIdx.x * 256 + t;
  sm[t] = (i < N) ? deg[i] : 0;
  __syncthreads();
#pragma unroll
  for (int s = 128; s > 0; s >>= 1) {
    if (t < s) sm[t] += sm[t + s];
    __syncthreads();
  }
  if (t == 0) partial[blockIdx.x] = sm[0];
}

__global__ void scan_offsets_kernel(int* __restrict__ partial, int nb) {
  __shared__ int sm[256];
  int t = threadIdx.x;
  int v = (t < nb) ? partial[t] : 0;
  sm[t] = v;
  __syncthreads();
#pragma unroll
  for (int off = 1; off < 256; off <<= 1) {
    int a = (t >= off) ? sm[t - off] : 0;
    __syncthreads();
    sm[t] += a;
    __syncthreads();
  }
  if (t < nb) partial[t] = sm[t] - v;  // exclusive
}

__global__ void scan_final_kernel(const int* __restrict__ deg, const int* __restrict__ partial,
                                  int* __restrict__ rowptr, int* __restrict__ cursor, int N, int E) {
  __shared__ int sm[256];
  int t = threadIdx.x;
  int i = blockIdx.x * 256 + t;
  int v = (i < N) ? deg[i] : 0;
  sm[t] = v;
  __syncthreads();
#pragma unroll
  for (int off = 1; off < 256; off <<= 1) {
    int a = (t >= off) ? sm[t - off] : 0;
    __syncthreads();
    sm[t] += a;
    __syncthreads();
  }
  if (i < N) {
    int ex = partial[blockIdx.x] + sm[t] - v;
    rowptr[i] = ex;
    cursor[i] = ex;
  }
  if (i == 0) rowptr[N] = E;
}

// edges packed as (src, ea_bits) for a single dwordx2 per edge
__global__ void scatter_build_kernel(const int* __restrict__ src, const int* __restrict__ dst,
                                     const float* __restrict__ ea, int* __restrict__ cursor,
                                     int2* __restrict__ edg, int E) {
  int e = blockIdx.x * blockDim.x + threadIdx.x;
  if (e >= E) return;
  int d = dst[e];
  int pos = atomicAdd(&cursor[d], 1);
  edg[pos] = make_int2(src[e], __float_as_int(ea[e]));
}

// ---------------- async global->LDS helpers ----------------
typedef const __attribute__((address_space(1))) void* gas_p;
typedef __attribute__((address_space(3))) void* las_p;
__device__ __forceinline__ void load_lds16(const void* g, void* l) {
  // one VMEM instr: 64 lanes x 16B; LDS dest = uniform base + lane*16
  __builtin_amdgcn_global_load_lds((gas_p)g, (las_p)l, 16, 0, 0);
}
// s_waitcnt imm: vmcnt[3:0]=bits3:0, expcnt=bits6:4(7=nowait), lgkmcnt=bits11:8(15=nowait)
#define WAITVM(v) __builtin_amdgcn_s_waitcnt(0xF70 | (v))
__device__ __forceinline__ void waitvm_rt(int v) {
  switch (v) {
    case 0: WAITVM(0); break;
    case 1: WAITVM(1); break;
    case 2: WAITVM(2); break;
    case 3: WAITVM(3); break;
    default: WAITVM(4); break;
  }
}

// ---------------- fused GATv2: deep-pipelined gather + softmax + aggregate ----------------
__device__ __forceinline__ void edge_accum(const float4 xlv, const float eav,
                                           const float4 xr4, const float4 We4, const float4 at4,
                                           float4& acc, float& denom) {
  float4 v;
  v.x = fmaf(eav, We4.x, xlv.x + xr4.x);
  v.y = fmaf(eav, We4.y, xlv.y + xr4.y);
  v.z = fmaf(eav, We4.z, xlv.z + xr4.z);
  v.w = fmaf(eav, We4.w, xlv.w + xr4.w);
  v.x = (v.x >= 0.f) ? v.x : 0.2f * v.x;
  v.y = (v.y >= 0.f) ? v.y : 0.2f * v.y;
  v.z = (v.z >= 0.f) ? v.z : 0.2f * v.z;
  v.w = (v.w >= 0.f) ? v.w : 0.2f * v.w;
  float p = v.x * at4.x + v.y * at4.y + v.z * at4.z + v.w * at4.w;
  p += __shfl_xor(p, 1, 64);
  p += __shfl_xor(p, 2, 64);
  p += __shfl_xor(p, 4, 64);
  p += __shfl_xor(p, 8, 64);   // all 16 lanes of the head group hold alpha_h
  float ex = __expf(p);
  denom += ex;
  acc.x = fmaf(ex, xlv.x, acc.x);
  acc.y = fmaf(ex, xlv.y, acc.y);
  acc.z = fmaf(ex, xlv.z, acc.z);
  acc.w = fmaf(ex, xlv.w, acc.w);
}

// One wave per node. 7 LDS row slots/wave, 6 row-fetches in flight via
// global_load_lds; edge meta staged to LDS (128 edges per instr) so no
// register-bound global loads (and no compiler vmcnt drains) in the loop.
template <bool POOL>
__global__ __launch_bounds__(256) void gat_aggregate_kernel(
    const int* __restrict__ rowptr, const int2* __restrict__ edg,
    const float* __restrict__ xl, const float* __restrict__ xr,
    const float* __restrict__ We, const float* __restrict__ att,
    const float* __restrict__ bias, float* __restrict__ out,
    const int* __restrict__ batch, float* __restrict__ sums, float* __restrict__ cnt,
    int N) {
  constexpr int P = 7;                       // slots; P-1=6 fetches in flight
  __shared__ __align__(16) char smem[4 * (1024 + P * 1024)];
  int wib = threadIdx.x >> 6;
  int lane = threadIdx.x & 63;
  int d = blockIdx.x * 4 + wib;
  if (d >= N) return;                        // no barriers used anywhere below
  char* wbase = smem + wib * (1024 + P * 1024);
  int2* meta = (int2*)wbase;                 // 128 edges of (src, ea)
  float* slots = (float*)(wbase + 1024);     // P x 256 floats

  float4 xr4 = ((const float4*)xr)[(size_t)d * 64 + lane];
  float4 We4 = ((const float4*)We)[lane];
  float4 at4 = ((const float4*)att)[lane];
  int beg = rowptr[d], end = rowptr[d + 1];
  float4 acc = {0.f, 0.f, 0.f, 0.f};
  float denom = 0.f;

  for (int cbeg = beg; cbeg < end; cbeg += 128) {
    int L = end - cbeg; if (L > 128) L = 128;
    // stage meta (overfetch beyond chunk stays inside workspace)
    load_lds16((const char*)(edg + cbeg) + lane * 16, meta);
    WAITVM(0);                               // meta ready (prev chunk already drained)
    int F = (L < P - 1) ? L : (P - 1);
    // prologue: issue F row fetches
#pragma unroll
    for (int k = 0; k < P - 1; ++k) {
      if (k < F) {
        int s = meta[k].x;
        load_lds16((const char*)(xl + (size_t)s * 256) + lane * 16, slots + k * 256);
      }
    }
    int j = 0, cs = 0, is_ = F;
    // steady state: constant vmcnt(P-2), never a full drain
    for (; j <= L - P + 1; ++j) {
      WAITVM(P - 2);
      int2 mm = meta[j];
      float4 a = ((const float4*)(slots + cs * 256))[lane];
      edge_accum(a, __int_as_float(mm.y), xr4, We4, at4, acc, denom);
      int nx = j + P - 1;
      if (nx < L) {
        int s = meta[nx].x;
        load_lds16((const char*)(xl + (size_t)s * 256) + lane * 16, slots + is_ * 256);
        if (++is_ == P) is_ = 0;
      }
      if (++cs == P) cs = 0;
    }
    // tail ladder: descending waits, ends drained (vmcnt 0)
#pragma unroll
    for (int k = P - 3; k >= 0; --k) {
      if (j < L && (L - 1 - j) == k) {
        waitvm_rt(k);
        int2 mm = meta[j];
        float4 a = ((const float4*)(slots + cs * 256))[lane];
        edge_accum(a, __int_as_float(mm.y), xr4, We4, at4, acc, denom);
        if (++cs == P) cs = 0;
        ++j;
      }
    }
  }

  float inv = 1.f / (denom + 1e-16f);
  float4 b4 = ((const float4*)bias)[lane];
  float4 o;
  o.x = fmaxf(fmaf(acc.x, inv, b4.x), 0.f);
  o.y = fmaxf(fmaf(acc.y, inv, b4.y), 0.f);
  o.z = fmaxf(fmaf(acc.z, inv, b4.z), 0.f);
  o.w = fmaxf(fmaf(acc.w, inv, b4.w), 0.f);
  if (POOL) {
    int g = batch[d];
    float* sg = sums + (size_t)g * 256 + lane * 4;
    atomicAdd(sg + 0, o.x);
    atomicAdd(sg + 1, o.y);
    atomicAdd(sg + 2, o.z);
    atomicAdd(sg + 3, o.w);
    if (lane == 0) atomicAdd(&cnt[g], 1.0f);
  } else {
    ((float4*)out)[(size_t)d * 64 + lane] = o;
  }
}

// ---------------- per-graph MLP head ----------------
__global__ void mlp_kernel(const float* __restrict__ sums, const float* __restrict__ cnt,
                           const float* __restrict__ p1W, const float* __restrict__ p1b,
                           const float* __restrict__ lng, const float* __restrict__ lnb,
                           const float* __restrict__ p2W, const float* __restrict__ p2b,
                           float* __restrict__ outp, int G) {
  __shared__ float p[256];
  __shared__ float z[128];
  __shared__ float wsum[2];
  __shared__ float wsum2[2];
  int g = blockIdx.x;
  int t = threadIdx.x;  // 0..127
  float c = fmaxf(cnt[g], 1.0f);
  p[t] = sums[(size_t)g * 256 + t] / c;
  p[t + 128] = sums[(size_t)g * 256 + t + 128] / c;
  __syncthreads();
  float acc = p1b[t];
  for (int k = 0; k < 256; ++k) acc = fmaf(p[k], p1W[k * 128 + t], acc);
  float v = acc;
#pragma unroll
  for (int off = 32; off > 0; off >>= 1) v += __shfl_xor(v, off, 64);
  if ((t & 63) == 0) wsum[t >> 6] = v;
  __syncthreads();
  float mu = (wsum[0] + wsum[1]) * (1.0f / 128.0f);
  float dv = acc - mu;
  float vv = dv * dv;
#pragma unroll
  for (int off = 32; off > 0; off >>= 1) vv += __shfl_xor(vv, off, 64);
  if ((t & 63) == 0) wsum2[t >> 6] = vv;
  __syncthreads();
  float var = (wsum2[0] + wsum2[1]) * (1.0f / 128.0f);
  float zv = dv * rsqrtf(var + 1e-5f) * lng[t] + lnb[t];
  z[t] = fmaxf(zv, 0.0f);
  __syncthreads();
  if (t < 64) {
    float o = p2b[t];
    for (int k = 0; k < 128; ++k) o = fmaf(z[k], p2W[k * 64 + t], o);
    outp[(size_t)g * 64 + t] = fmaxf(o, 0.0f);
  }
}

extern "C" void kernel_launch(void* const* d_in, const int* in_sizes, int n_in,
                              void* d_out, int out_size, void* d_ws, size_t ws_size,
                              hipStream_t stream) {
  const float* x      = (const float*)d_in[0];
  const int*   ei     = (const int*)d_in[1];
  const float* ea     = (const float*)d_in[2];
  const int*   batch  = (const int*)d_in[3];
  const float* enc_W  = (const float*)d_in[4];
  const float* enc_b  = (const float*)d_in[5];
  const float* Wl1    = (const float*)d_in[6];
  const float* bl1    = (const float*)d_in[7];
  const float* Wr1    = (const float*)d_in[8];
  const float* br1    = (const float*)d_in[9];
  const float* We1    = (const float*)d_in[10];
  const float* att1   = (const float*)d_in[11];
  const float* bias1  = (const float*)d_in[12];
  const float* Wl2    = (const float*)d_in[13];
  const float* bl2    = (const float*)d_in[14];
  const float* Wr2    = (const float*)d_in[15];
  const float* br2    = (const float*)d_in[16];
  const float* We2    = (const float*)d_in[17];
  const float* att2   = (const float*)d_in[18];
  const float* bias2  = (const float*)d_in[19];
  const float* p1W    = (const float*)d_in[20];
  const float* p1b    = (const float*)d_in[21];
  const float* lng    = (const float*)d_in[22];
  const float* lnb    = (const float*)d_in[23];
  const float* p2W    = (const float*)d_in[24];
  const float* p2b    = (const float*)d_in[25];
  float* outp = (float*)d_out;

  int N = in_sizes[0] / 8;
  int E = in_sizes[2];
  int G = out_size / 64;
  const int* src = ei;
  const int* dst = ei + E;
  int nb = (N + 255) / 256;   // <=256 scan blocks (N=50000 -> 196)

  // workspace layout
  float* ws      = (float*)d_ws;
  float* h0      = ws;                          // N*64
  float* B0      = h0     + (size_t)N * 64;     // N*256 (xl, fp32)
  float* B1      = B0     + (size_t)N * 256;    // N*256 (xr)
  float* B2      = B1     + (size_t)N * 256;    // N*256 (layer1 out)
  float* sums    = B2     + (size_t)N * 256;    // G*256
  float* cnt     = sums   + (size_t)G * 256;    // G
  int2*  edg     = (int2*)(cnt + G);            // E (src, ea) — 16B aligned
  int*   rowptr  = (int*)(edg + (size_t)E);     // N+1 (also absorbs meta overfetch)
  int*   cursor  = rowptr + (size_t)(N + 1);    // N
  int*   partial = cursor + (size_t)N;          // nb

  // encoder
  encoder_kernel<<<(N * 64 + 255) / 256, 256, 0, stream>>>(x, enc_W, enc_b, h0, N);

  // CSR build (shared by both layers — dst is static)
  hipMemsetAsync(cursor, 0, (size_t)N * sizeof(int), stream);
  hist_kernel<<<(E + 255) / 256, 256, 0, stream>>>(dst, cursor, E);
  scan_partial_kernel<<<nb, 256, 0, stream>>>(cursor, partial, N);
  scan_offsets_kernel<<<1, 256, 0, stream>>>(partial, nb);
  scan_final_kernel<<<nb, 256, 0, stream>>>(cursor, partial, rowptr, cursor, N, E);
  scatter_build_kernel<<<(E + 255) / 256, 256, 0, stream>>>(src, dst, ea, cursor, edg, E);

  // GAT layer 1 (K=64): h0 -> B2
  lin_lr_kernel<64><<<(N + 7) / 8, 256, 0, stream>>>(h0, Wl1, bl1, Wr1, br1, B0, B1, N);
  gat_aggregate_kernel<false><<<(N + 3) / 4, 256, 0, stream>>>(
      rowptr, edg, B0, B1, We1, att1, bias1, B2, nullptr, nullptr, nullptr, N);

  // GAT layer 2 (K=256): B2 -> pooled sums directly
  lin_lr_kernel<256><<<(N + 7) / 8, 256, 0, stream>>>(B2, Wl2, bl2, Wr2, br2, B0, B1, N);
  hipMemsetAsync(sums, 0, ((size_t)G * 256 + G) * sizeof(float), stream);
  gat_aggregate_kernel<true><<<(N + 3) / 4, 256, 0, stream>>>(
      rowptr, edg, B0, B1, We2, att2, bias2, nullptr, batch, sums, cnt, N);

  // per-graph MLP
  mlp_kernel<<<G, 128, 0, stream>>>(sums, cnt, p1W, p1b, lng, lnb, p2W, p2b, outp, G);
}

// Round 8
// 1080.620 us; speedup vs baseline: 1.0891x; 1.0891x over previous
//
#include <hip/hip_runtime.h>

#define NH 4     // heads
#define CH 64    // channels/head

// ---------------- encoder: h = relu(x @ W + b); x:[N,8], W:[8,64] ----------------
__global__ void encoder_kernel(const float* __restrict__ x, const float* __restrict__ W,
                               const float* __restrict__ b, float* __restrict__ h, int N) {
  int idx = blockIdx.x * blockDim.x + threadIdx.x;
  if (idx >= N * 64) return;
  int n = idx >> 6, j = idx & 63;
  const float* xp = x + n * 8;
  float acc = b[j];
#pragma unroll
  for (int k = 0; k < 8; ++k) acc = fmaf(xp[k], W[k * 64 + j], acc);
  h[idx] = fmaxf(acc, 0.0f);
}

// ------- xl = h@Wl + bl, xr = h@Wr + br (both fp32); h:[N,K], W:[K,256] -------
template <int K>
__global__ void lin_lr_kernel(const float* __restrict__ h,
                              const float* __restrict__ Wl, const float* __restrict__ bl,
                              const float* __restrict__ Wr, const float* __restrict__ br,
                              float* __restrict__ xl, float* __restrict__ xr, int N) {
  __shared__ float hs[8][K];
  int n0 = blockIdx.x * 8;
  int j = threadIdx.x;  // output column
  int nmax = N - n0; if (nmax > 8) nmax = 8;
  for (int idx = j; idx < nmax * K; idx += 256) {
    int m = idx / K, k = idx % K;
    hs[m][k] = h[(size_t)(n0 + m) * K + k];
  }
  __syncthreads();
  float accl[8], accr[8];
  float bjl = bl[j], bjr = br[j];
#pragma unroll
  for (int m = 0; m < 8; ++m) { accl[m] = bjl; accr[m] = bjr; }
  for (int k = 0; k < K; ++k) {
    float wl = Wl[k * 256 + j];
    float wr = Wr[k * 256 + j];
#pragma unroll
    for (int m = 0; m < 8; ++m) {
      accl[m] = fmaf(hs[m][k], wl, accl[m]);
      accr[m] = fmaf(hs[m][k], wr, accr[m]);
    }
  }
  for (int m = 0; m < nmax; ++m) {
    xl[(size_t)(n0 + m) * 256 + j] = accl[m];
    xr[(size_t)(n0 + m) * 256 + j] = accr[m];
  }
}

// ---------------- CSR build (counting sort by dst), fully parallel scan ----------------
__global__ void hist_kernel(const int* __restrict__ dst, int* __restrict__ deg, int E) {
  int e = blockIdx.x * blockDim.x + threadIdx.x;
  if (e < E) atomicAdd(&deg[dst[e]], 1);
}

__global__ void scan_partial_kernel(const int* __restrict__ deg, int* __restrict__ partial, int N) {
  __shared__ int sm[256];
  int t = threadIdx.x;
  int i = blockIdx.x * 256 + t;
  sm[t] = (i < N) ? deg[i] : 0;
  __syncthreads();
#pragma unroll
  for (int s = 128; s > 0; s >>= 1) {
    if (t < s) sm[t] += sm[t + s];
    __syncthreads();
  }
  if (t == 0) partial[blockIdx.x] = sm[0];
}

__global__ void scan_offsets_kernel(int* __restrict__ partial, int nb) {
  __shared__ int sm[256];
  int t = threadIdx.x;
  int v = (t < nb) ? partial[t] : 0;
  sm[t] = v;
  __syncthreads();
#pragma unroll
  for (int off = 1; off < 256; off <<= 1) {
    int a = (t >= off) ? sm[t - off] : 0;
    __syncthreads();
    sm[t] += a;
    __syncthreads();
  }
  if (t < nb) partial[t] = sm[t] - v;  // exclusive
}

__global__ void scan_final_kernel(const int* __restrict__ deg, const int* __restrict__ partial,
                                  int* __restrict__ rowptr, int* __restrict__ cursor, int N, int E) {
  __shared__ int sm[256];
  int t = threadIdx.x;
  int i = blockIdx.x * 256 + t;
  int v = (i < N) ? deg[i] : 0;
  sm[t] = v;
  __syncthreads();
#pragma unroll
  for (int off = 1; off < 256; off <<= 1) {
    int a = (t >= off) ? sm[t - off] : 0;
    __syncthreads();
    sm[t] += a;
    __syncthreads();
  }
  if (i < N) {
    int ex = partial[blockIdx.x] + sm[t] - v;
    rowptr[i] = ex;
    cursor[i] = ex;
  }
  if (i == 0) rowptr[N] = E;
}

// edges packed as (src, ea_bits) for a single dwordx2 per edge
__global__ void scatter_build_kernel(const int* __restrict__ src, const int* __restrict__ dst,
                                     const float* __restrict__ ea, int* __restrict__ cursor,
                                     int2* __restrict__ edg, int E) {
  int e = blockIdx.x * blockDim.x + threadIdx.x;
  if (e >= E) return;
  int d = dst[e];
  int pos = atomicAdd(&cursor[d], 1);
  edg[pos] = make_int2(src[e], __float_as_int(ea[e]));
}

// ---------------- fused GATv2: alpha + softmax + aggregate + bias + relu ----------------
__device__ __forceinline__ void edge_accum(const float4 xlv, const float eav,
                                           const float4 xr4, const float4 We4, const float4 at4,
                                           float4& acc, float& denom) {
  float4 v;
  v.x = fmaf(eav, We4.x, xlv.x + xr4.x);
  v.y = fmaf(eav, We4.y, xlv.y + xr4.y);
  v.z = fmaf(eav, We4.z, xlv.z + xr4.z);
  v.w = fmaf(eav, We4.w, xlv.w + xr4.w);
  v.x = (v.x >= 0.f) ? v.x : 0.2f * v.x;
  v.y = (v.y >= 0.f) ? v.y : 0.2f * v.y;
  v.z = (v.z >= 0.f) ? v.z : 0.2f * v.z;
  v.w = (v.w >= 0.f) ? v.w : 0.2f * v.w;
  float p = v.x * at4.x + v.y * at4.y + v.z * at4.z + v.w * at4.w;
  p += __shfl_xor(p, 1, 64);
  p += __shfl_xor(p, 2, 64);
  p += __shfl_xor(p, 4, 64);
  p += __shfl_xor(p, 8, 64);   // all 16 lanes of the head group hold alpha_h
  float ex = __expf(p);
  denom += ex;
  acc.x = fmaf(ex, xlv.x, acc.x);
  acc.y = fmaf(ex, xlv.y, acc.y);
  acc.z = fmaf(ex, xlv.z, acc.z);
  acc.w = fmaf(ex, xlv.w, acc.w);
}

// One wave per node. Edge meta for 64 edges lives in REGISTERS (lane j holds
// edge j); per-edge (src,ea) distributed via __shfl (ds_bpermute -> lgkmcnt,
// never drains vmcnt). Row gathers software-pipelined 2 groups x 4 deep:
// 8 x 1KB continuously in flight per wave. No LDS -> high occupancy.
template <bool POOL>
__global__ __launch_bounds__(256) void gat_aggregate_kernel(
    const int* __restrict__ rowptr, const int2* __restrict__ edg,
    const float* __restrict__ xl, const float* __restrict__ xr,
    const float* __restrict__ We, const float* __restrict__ att,
    const float* __restrict__ bias, float* __restrict__ out,
    const int* __restrict__ batch, float* __restrict__ sums, float* __restrict__ cnt,
    int N) {
  int d = (int)((blockIdx.x * (size_t)blockDim.x + threadIdx.x) >> 6);
  int lane = threadIdx.x & 63;
  if (d >= N) return;
  const float4* xlp = (const float4*)xl;
  float4 xr4 = ((const float4*)xr)[(size_t)d * 64 + lane];
  float4 We4 = ((const float4*)We)[lane];
  float4 at4 = ((const float4*)att)[lane];
  int beg = rowptr[d], end = rowptr[d + 1];
  float4 acc = {0.f, 0.f, 0.f, 0.f};
  float denom = 0.f;

  for (int cb = beg; cb < end; cb += 64) {
    int L = end - cb; if (L > 64) L = 64;
    int2 m = edg[cb + lane];             // 64 edge metas -> registers (1 instr)
    float mea = __int_as_float(m.y);
    int j = 0;
    float4 c0, c1, c2, c3;
    float ce0, ce1, ce2, ce3;
    if (j + 3 < L) {                     // prologue: group 0 in flight
      int s0 = __shfl(m.x, 0), s1 = __shfl(m.x, 1), s2 = __shfl(m.x, 2), s3 = __shfl(m.x, 3);
      ce0 = __shfl(mea, 0); ce1 = __shfl(mea, 1); ce2 = __shfl(mea, 2); ce3 = __shfl(mea, 3);
      c0 = xlp[(size_t)s0 * 64 + lane];
      c1 = xlp[(size_t)s1 * 64 + lane];
      c2 = xlp[(size_t)s2 * 64 + lane];
      c3 = xlp[(size_t)s3 * 64 + lane];
    }
    for (; j + 7 < L; j += 4) {          // steady state: issue next 4 BEFORE consuming
      int s0 = __shfl(m.x, j + 4), s1 = __shfl(m.x, j + 5);
      int s2 = __shfl(m.x, j + 6), s3 = __shfl(m.x, j + 7);
      float ne0 = __shfl(mea, j + 4), ne1 = __shfl(mea, j + 5);
      float ne2 = __shfl(mea, j + 6), ne3 = __shfl(mea, j + 7);
      float4 n0 = xlp[(size_t)s0 * 64 + lane];
      float4 n1 = xlp[(size_t)s1 * 64 + lane];
      float4 n2 = xlp[(size_t)s2 * 64 + lane];
      float4 n3 = xlp[(size_t)s3 * 64 + lane];
      edge_accum(c0, ce0, xr4, We4, at4, acc, denom);
      edge_accum(c1, ce1, xr4, We4, at4, acc, denom);
      edge_accum(c2, ce2, xr4, We4, at4, acc, denom);
      edge_accum(c3, ce3, xr4, We4, at4, acc, denom);
      c0 = n0; c1 = n1; c2 = n2; c3 = n3;
      ce0 = ne0; ce1 = ne1; ce2 = ne2; ce3 = ne3;
    }
    if (j + 3 < L) {                     // drain last full group
      edge_accum(c0, ce0, xr4, We4, at4, acc, denom);
      edge_accum(c1, ce1, xr4, We4, at4, acc, denom);
      edge_accum(c2, ce2, xr4, We4, at4, acc, denom);
      edge_accum(c3, ce3, xr4, We4, at4, acc, denom);
      j += 4;
    }
    for (; j < L; ++j) {                 // tail singles
      int s0 = __shfl(m.x, j);
      float e0 = __shfl(mea, j);
      float4 a0 = xlp[(size_t)s0 * 64 + lane];
      edge_accum(a0, e0, xr4, We4, at4, acc, denom);
    }
  }

  float inv = 1.f / (denom + 1e-16f);
  float4 b4 = ((const float4*)bias)[lane];
  float4 o;
  o.x = fmaxf(fmaf(acc.x, inv, b4.x), 0.f);
  o.y = fmaxf(fmaf(acc.y, inv, b4.y), 0.f);
  o.z = fmaxf(fmaf(acc.z, inv, b4.z), 0.f);
  o.w = fmaxf(fmaf(acc.w, inv, b4.w), 0.f);
  if (POOL) {
    int g = batch[d];
    float* sg = sums + (size_t)g * 256 + lane * 4;
    atomicAdd(sg + 0, o.x);
    atomicAdd(sg + 1, o.y);
    atomicAdd(sg + 2, o.z);
    atomicAdd(sg + 3, o.w);
    if (lane == 0) atomicAdd(&cnt[g], 1.0f);
  } else {
    ((float4*)out)[(size_t)d * 64 + lane] = o;
  }
}

// ---------------- per-graph MLP head ----------------
__global__ void mlp_kernel(const float* __restrict__ sums, const float* __restrict__ cnt,
                           const float* __restrict__ p1W, const float* __restrict__ p1b,
                           const float* __restrict__ lng, const float* __restrict__ lnb,
                           const float* __restrict__ p2W, const float* __restrict__ p2b,
                           float* __restrict__ outp, int G) {
  __shared__ float p[256];
  __shared__ float z[128];
  __shared__ float wsum[2];
  __shared__ float wsum2[2];
  int g = blockIdx.x;
  int t = threadIdx.x;  // 0..127
  float c = fmaxf(cnt[g], 1.0f);
  p[t] = sums[(size_t)g * 256 + t] / c;
  p[t + 128] = sums[(size_t)g * 256 + t + 128] / c;
  __syncthreads();
  float acc = p1b[t];
  for (int k = 0; k < 256; ++k) acc = fmaf(p[k], p1W[k * 128 + t], acc);
  float v = acc;
#pragma unroll
  for (int off = 32; off > 0; off >>= 1) v += __shfl_xor(v, off, 64);
  if ((t & 63) == 0) wsum[t >> 6] = v;
  __syncthreads();
  float mu = (wsum[0] + wsum[1]) * (1.0f / 128.0f);
  float dv = acc - mu;
  float vv = dv * dv;
#pragma unroll
  for (int off = 32; off > 0; off >>= 1) vv += __shfl_xor(vv, off, 64);
  if ((t & 63) == 0) wsum2[t >> 6] = vv;
  __syncthreads();
  float var = (wsum2[0] + wsum2[1]) * (1.0f / 128.0f);
  float zv = dv * rsqrtf(var + 1e-5f) * lng[t] + lnb[t];
  z[t] = fmaxf(zv, 0.0f);
  __syncthreads();
  if (t < 64) {
    float o = p2b[t];
    for (int k = 0; k < 128; ++k) o = fmaf(z[k], p2W[k * 64 + t], o);
    outp[(size_t)g * 64 + t] = fmaxf(o, 0.0f);
  }
}

extern "C" void kernel_launch(void* const* d_in, const int* in_sizes, int n_in,
                              void* d_out, int out_size, void* d_ws, size_t ws_size,
                              hipStream_t stream) {
  const float* x      = (const float*)d_in[0];
  const int*   ei     = (const int*)d_in[1];
  const float* ea     = (const float*)d_in[2];
  const int*   batch  = (const int*)d_in[3];
  const float* enc_W  = (const float*)d_in[4];
  const float* enc_b  = (const float*)d_in[5];
  const float* Wl1    = (const float*)d_in[6];
  const float* bl1    = (const float*)d_in[7];
  const float* Wr1    = (const float*)d_in[8];
  const float* br1    = (const float*)d_in[9];
  const float* We1    = (const float*)d_in[10];
  const float* att1   = (const float*)d_in[11];
  const float* bias1  = (const float*)d_in[12];
  const float* Wl2    = (const float*)d_in[13];
  const float* bl2    = (const float*)d_in[14];
  const float* Wr2    = (const float*)d_in[15];
  const float* br2    = (const float*)d_in[16];
  const float* We2    = (const float*)d_in[17];
  const float* att2   = (const float*)d_in[18];
  const float* bias2  = (const float*)d_in[19];
  const float* p1W    = (const float*)d_in[20];
  const float* p1b    = (const float*)d_in[21];
  const float* lng    = (const float*)d_in[22];
  const float* lnb    = (const float*)d_in[23];
  const float* p2W    = (const float*)d_in[24];
  const float* p2b    = (const float*)d_in[25];
  float* outp = (float*)d_out;

  int N = in_sizes[0] / 8;
  int E = in_sizes[2];
  int G = out_size / 64;
  const int* src = ei;
  const int* dst = ei + E;
  int nb = (N + 255) / 256;   // <=256 scan blocks (N=50000 -> 196)

  // workspace layout
  float* ws      = (float*)d_ws;
  float* h0      = ws;                          // N*64
  float* B0      = h0     + (size_t)N * 64;     // N*256 (xl)
  float* B1      = B0     + (size_t)N * 256;    // N*256 (xr)
  float* B2      = B1     + (size_t)N * 256;    // N*256 (layer1 out)
  float* sums    = B2     + (size_t)N * 256;    // G*256
  float* cnt     = sums   + (size_t)G * 256;    // G
  int2*  edg     = (int2*)(cnt + G);            // E+64 (src, ea); +64 pad for meta overread
  int*   rowptr  = (int*)(edg + (size_t)E + 64);// N+1
  int*   cursor  = rowptr + (size_t)(N + 1);    // N
  int*   partial = cursor + (size_t)N;          // nb

  // encoder
  encoder_kernel<<<(N * 64 + 255) / 256, 256, 0, stream>>>(x, enc_W, enc_b, h0, N);

  // CSR build (shared by both layers — dst is static)
  hipMemsetAsync(cursor, 0, (size_t)N * sizeof(int), stream);
  hist_kernel<<<(E + 255) / 256, 256, 0, stream>>>(dst, cursor, E);
  scan_partial_kernel<<<nb, 256, 0, stream>>>(cursor, partial, N);
  scan_offsets_kernel<<<1, 256, 0, stream>>>(partial, nb);
  scan_final_kernel<<<nb, 256, 0, stream>>>(cursor, partial, rowptr, cursor, N, E);
  scatter_build_kernel<<<(E + 255) / 256, 256, 0, stream>>>(src, dst, ea, cursor, edg, E);

  // GAT layer 1 (K=64): h0 -> B2
  lin_lr_kernel<64><<<(N + 7) / 8, 256, 0, stream>>>(h0, Wl1, bl1, Wr1, br1, B0, B1, N);
  gat_aggregate_kernel<false><<<(N + 3) / 4, 256, 0, stream>>>(
      rowptr, edg, B0, B1, We1, att1, bias1, B2, nullptr, nullptr, nullptr, N);

  // GAT layer 2 (K=256): B2 -> pooled sums directly
  lin_lr_kernel<256><<<(N + 7) / 8, 256, 0, stream>>>(B2, Wl2, bl2, Wr2, br2, B0, B1, N);
  hipMemsetAsync(sums, 0, ((size_t)G * 256 + G) * sizeof(float), stream);
  gat_aggregate_kernel<true><<<(N + 3) / 4, 256, 0, stream>>>(
      rowptr, edg, B0, B1, We2, att2, bias2, nullptr, batch, sums, cnt, N);

  // per-graph MLP
  mlp_kernel<<<G, 128, 0, stream>>>(sums, cnt, p1W, p1b, lng, lnb, p2W, p2b, outp, G);
}